// Round 2
// baseline (252.134 us; speedup 1.0000x reference)
//
#include <hip/hip_runtime.h>
#include <stdint.h>

#define HW 625              // 25*25
#define NROT 6
#define C_OUT 161
#define OUT_PER_B (C_OUT * HW)   // 100625
#define IN_PER_B  (128 * HW)     // 80000
#define NT 256

__global__ __launch_bounds__(NT)
void env_embed(const float* __restrict__ sta, const float* __restrict__ dyn,
               const float* __restrict__ obst, const float* __restrict__ ocur,
               const float* __restrict__ omem, const float* __restrict__ pvis,
               const float* __restrict__ atgt, const float* __restrict__ ptgt,
               const float* __restrict__ lead, const float* __restrict__ foll,
               const int* __restrict__ rots, float* __restrict__ out)
{
    const int b = blockIdx.x;
    const int t = threadIdx.x;
    const int rot = rots[b];                 // block-uniform -> scalar
    __shared__ float lds_obs[HW];

    const int bHW = b * HW;
    float* const out_b = out + (size_t)b * OUT_PER_B;

    // ---- Phase 1: channels 128..160 + stage obs_mem plane into LDS ----
    for (int p = t; p < HW; p += NT) {
        const float obs = omem[bHW + p];
        lds_obs[p] = obs;
        float* const ob = out_b + p;

        ob[128 * HW] = obst[bHW + p] * obs;
        ob[129 * HW] = ocur[bHW + p] * obs;
        ob[130 * HW] = obs * obs;
        ob[138 * HW] = lead[bHW + p] * obs;
        ob[139 * HW] = foll[bHW + p] * obs;

        float s_pv = 0.f, s_at = 0.f, s_pt = 0.f;
        #pragma unroll
        for (int r = 0; r < NROT; ++r) {     // iterate SOURCE rotation
            const float pv = pvis[(b * NROT + r) * HW + p];
            const float at = atgt[(b * NROT + r) * HW + p];
            const float pt = ptgt[(b * NROT + r) * HW + p];
            s_pv += pv; s_at += at; s_pt += pt;
            int j = r + rot; if (j >= NROT) j -= NROT;   // dest channel
            ob[(131 + j) * HW] = pv * 0.5f * obs;
            ob[(140 + j) * HW] = at * 0.5f * obs;
            ob[(146 + j) * HW] = pt * obs;
        }
        ob[137 * HW] = s_pv * obs;           // all_visitations (unscaled sum)
        ob[152 * HW] = s_at * 0.5f * obs;    // sum of scaled targets
        ob[153 * HW] = s_pt * obs;
        ob[154 * HW] = 1.0f;                 // ones channel (not scaled)
        #pragma unroll
        for (int j = 0; j < NROT; ++j)       // compass one-hot (not scaled)
            ob[(155 + j) * HW] = (j == rot) ? 1.0f : 0.0f;
    }

    __syncthreads();

    // ---- Phase 2: channels 0..127 : (sta+dyn)*obs, flat over 80000 elems ----
    const float* const sb = sta + (size_t)b * IN_PER_B;   // 16B-aligned (b*320000 B)
    const float* const db = dyn + (size_t)b * IN_PER_B;
    const int amode = b & 3;   // output base misalignment in dwords (block-uniform)

    for (int k = t; k < IN_PER_B / 4; k += NT) {
        const int idx = 4 * k;
        const float4 s4 = *(const float4*)(sb + idx);     // aligned
        const float4 d4 = *(const float4*)(db + idx);     // aligned

        int q = idx % 625;                                // pixel of first elem
        const float o0 = lds_obs[q]; q = (q + 1 == HW) ? 0 : q + 1;
        const float o1 = lds_obs[q]; q = (q + 1 == HW) ? 0 : q + 1;
        const float o2 = lds_obs[q]; q = (q + 1 == HW) ? 0 : q + 1;
        const float o3 = lds_obs[q];

        const float r0 = (s4.x + d4.x) * o0;
        const float r1 = (s4.y + d4.y) * o1;
        const float r2 = (s4.z + d4.z) * o2;
        const float r3 = (s4.w + d4.w) * o3;

        float* const po = out_b + idx;       // byte align ≡ 4*b (mod 16)
        if (amode == 0) {
            *(float4*)po = make_float4(r0, r1, r2, r3);
        } else if (amode == 2) {             // 8B-aligned
            *(float2*)po       = make_float2(r0, r1);
            *(float2*)(po + 2) = make_float2(r2, r3);
        } else {                             // odd: scalar dwords (still coalesced)
            po[0] = r0; po[1] = r1; po[2] = r2; po[3] = r3;
        }
    }
}

extern "C" void kernel_launch(void* const* d_in, const int* in_sizes, int n_in,
                              void* d_out, int out_size, void* d_ws, size_t ws_size,
                              hipStream_t stream) {
    const float* sta  = (const float*)d_in[0];
    const float* dyn  = (const float*)d_in[1];
    const float* obst = (const float*)d_in[2];
    const float* ocur = (const float*)d_in[3];
    const float* omem = (const float*)d_in[4];
    const float* pvis = (const float*)d_in[5];
    const float* atgt = (const float*)d_in[6];
    const float* ptgt = (const float*)d_in[7];
    const float* lead = (const float*)d_in[8];
    const float* foll = (const float*)d_in[9];
    const int*   rots = (const int*)d_in[10];
    float* out = (float*)d_out;

    const int nb = in_sizes[10];             // batch count (1024)

    hipLaunchKernelGGL(env_embed, dim3(nb), dim3(NT), 0, stream,
                       sta, dyn, obst, ocur, omem, pvis, atgt, ptgt,
                       lead, foll, rots, out);
}

// Round 3
// 240.931 us; speedup vs baseline: 1.0465x; 1.0465x over previous
//
#include <hip/hip_runtime.h>
#include <stdint.h>

#define HW 625              // 25*25
#define NROT 6
#define C_OUT 161
#define OUT_PER_B (C_OUT * HW)   // 100625
#define IN_PER_B  (128 * HW)     // 80000
#define NT 256
#define QF  20000           // floats per quarter (32 channels * 625)
#define NF4 5000            // float4s per quarter
#define CST 629             // obs LDS copy stride; 629 % 4 == 1 -> conflict-free

__global__ __launch_bounds__(NT)
void env_embed(const float* __restrict__ sta, const float* __restrict__ dyn,
               const float* __restrict__ obst, const float* __restrict__ ocur,
               const float* __restrict__ omem, const float* __restrict__ pvis,
               const float* __restrict__ atgt, const float* __restrict__ ptgt,
               const float* __restrict__ lead, const float* __restrict__ foll,
               const int* __restrict__ rots, float* __restrict__ out, const int nb)
{
    const int bid = blockIdx.x;
    const int t = threadIdx.x;

    if (bid < nb) {
        // ================= small channels 128..160, one block per batch =========
        const int b = bid;
        const int rot = rots[b];             // block-uniform
        const int bHW = b * HW;
        float* const out_b = out + (size_t)b * OUT_PER_B;

        for (int p = t; p < HW; p += NT) {
            const float obs = omem[bHW + p];
            float* const ob = out_b + p;

            ob[128 * HW] = obst[bHW + p] * obs;
            ob[129 * HW] = ocur[bHW + p] * obs;
            ob[130 * HW] = obs * obs;
            ob[138 * HW] = lead[bHW + p] * obs;
            ob[139 * HW] = foll[bHW + p] * obs;

            float s_pv = 0.f, s_at = 0.f, s_pt = 0.f;
            #pragma unroll
            for (int r = 0; r < NROT; ++r) { // iterate SOURCE rotation
                const float pv = pvis[(b * NROT + r) * HW + p];
                const float at = atgt[(b * NROT + r) * HW + p];
                const float pt = ptgt[(b * NROT + r) * HW + p];
                s_pv += pv; s_at += at; s_pt += pt;
                int jj = r + rot; if (jj >= NROT) jj -= NROT;   // dest channel
                ob[(131 + jj) * HW] = pv * 0.5f * obs;
                ob[(140 + jj) * HW] = at * 0.5f * obs;
                ob[(146 + jj) * HW] = pt * obs;
            }
            ob[137 * HW] = s_pv * obs;
            ob[152 * HW] = s_at * 0.5f * obs;
            ob[153 * HW] = s_pt * obs;
            ob[154 * HW] = 1.0f;
            #pragma unroll
            for (int jj = 0; jj < NROT; ++jj)
                ob[(155 + jj) * HW] = (jj == rot) ? 1.0f : 0.0f;
        }
        return;
    }

    // ================= heavy channels: 4 blocks per batch, 32 channels each ====
    const int hb = bid - nb;
    const int b = hb >> 2;
    const int j = hb & 3;

    __shared__ float lobs[4 * CST];          // 4 bank-shifted copies of obs plane
    for (int p = t; p < HW; p += NT) {
        const float v = omem[b * HW + p];
        lobs[p] = v; lobs[CST + p] = v; lobs[2 * CST + p] = v; lobs[3 * CST + p] = v;
    }
    __syncthreads();

    const float* const sb = sta + (size_t)b * IN_PER_B + j * QF;   // 16B-aligned
    const float* const db = dyn + (size_t)b * IN_PER_B + j * QF;
    float* const ob = out + (size_t)b * OUT_PER_B + j * QF;        // align mod4 = b%4
    const float* const L = lobs + ((t >> 3) & 3) * CST;
    const int amode = b & 3;                 // block-uniform store-alignment mode

#define OBS4(Q, O0, O1, O2, O3) {                                  \
        int qq = (Q);                                              \
        O0 = L[qq]; qq = (qq == HW - 1) ? 0 : qq + 1;              \
        O1 = L[qq]; qq = (qq == HW - 1) ? 0 : qq + 1;              \
        O2 = L[qq]; qq = (qq == HW - 1) ? 0 : qq + 1;              \
        O3 = L[qq]; }

#define STORE4(PO, R0, R1, R2, R3) {                               \
        if (amode == 0)       *(float4*)(PO) = make_float4(R0, R1, R2, R3); \
        else if (amode == 2) { *(float2*)(PO) = make_float2(R0, R1);        \
                               *(float2*)((PO) + 2) = make_float2(R2, R3); }\
        else { (PO)[0] = R0; (PO)[1] = R1; (PO)[2] = R2; (PO)[3] = R3; } }

    int k = t;
    for (; k + NT < NF4; k += 2 * NT) {
        const int kB = k + NT;
        const int iA = 4 * k, iB = 4 * kB;
        // issue all global loads before any use
        const float4 sA = *(const float4*)(sb + iA);
        const float4 dA = *(const float4*)(db + iA);
        const float4 sB = *(const float4*)(sb + iB);
        const float4 dB = *(const float4*)(db + iB);

        float a0, a1, a2, a3, b0, b1, b2, b3;
        OBS4(iA % HW, a0, a1, a2, a3);
        OBS4(iB % HW, b0, b1, b2, b3);

        const float rA0 = (sA.x + dA.x) * a0, rA1 = (sA.y + dA.y) * a1;
        const float rA2 = (sA.z + dA.z) * a2, rA3 = (sA.w + dA.w) * a3;
        const float rB0 = (sB.x + dB.x) * b0, rB1 = (sB.y + dB.y) * b1;
        const float rB2 = (sB.z + dB.z) * b2, rB3 = (sB.w + dB.w) * b3;

        STORE4(ob + iA, rA0, rA1, rA2, rA3);
        STORE4(ob + iB, rB0, rB1, rB2, rB3);
    }
    if (k < NF4) {
        const int iA = 4 * k;
        const float4 sA = *(const float4*)(sb + iA);
        const float4 dA = *(const float4*)(db + iA);
        float a0, a1, a2, a3;
        OBS4(iA % HW, a0, a1, a2, a3);
        const float rA0 = (sA.x + dA.x) * a0, rA1 = (sA.y + dA.y) * a1;
        const float rA2 = (sA.z + dA.z) * a2, rA3 = (sA.w + dA.w) * a3;
        STORE4(ob + iA, rA0, rA1, rA2, rA3);
    }
#undef OBS4
#undef STORE4
}

extern "C" void kernel_launch(void* const* d_in, const int* in_sizes, int n_in,
                              void* d_out, int out_size, void* d_ws, size_t ws_size,
                              hipStream_t stream) {
    const float* sta  = (const float*)d_in[0];
    const float* dyn  = (const float*)d_in[1];
    const float* obst = (const float*)d_in[2];
    const float* ocur = (const float*)d_in[3];
    const float* omem = (const float*)d_in[4];
    const float* pvis = (const float*)d_in[5];
    const float* atgt = (const float*)d_in[6];
    const float* ptgt = (const float*)d_in[7];
    const float* lead = (const float*)d_in[8];
    const float* foll = (const float*)d_in[9];
    const int*   rots = (const int*)d_in[10];
    float* out = (float*)d_out;

    const int nb = in_sizes[10];             // batch count (1024)

    hipLaunchKernelGGL(env_embed, dim3(5 * nb), dim3(NT), 0, stream,
                       sta, dyn, obst, ocur, omem, pvis, atgt, ptgt,
                       lead, foll, rots, out, nb);
}